// Round 3
// baseline (177.866 us; speedup 1.0000x reference)
//
#include <hip/hip_runtime.h>

// LandmarkLoss, round 14. B=4, N=200000, K=64.
// R13 post-mortem: occupancy 25->51% yet 67->110us, VALUBusy 15%. Waves are
// contending for a serialized per-CU resource: the LDS pipe, dominated by the
// in-loop ds_atomic_min (64 distinct words/op, ~2cyc/word RMW ~= 130cyc/iter
// of serialized LDS time; per-CU totals reproduce 32/67/110us across R11-13).
// Fix: REMOVE the in-loop atomic. The bijection kk = lane^(wv<<4)^i makes
// lane d the unique visitor of target d^(wv<<4)^i each iteration, so route
// dl back with ONE ds_bpermute (addr = kk<<2, already computed): lane d pulls
// the value for target d and fminf's it into a home register. bpermute moves
// 256B (~3cyc) vs the atomic's ~128cyc. Per-wave LDS combine after the loop
// is 4 atomic wave-ops/block instead of 256.
// Carried from R13: P=2, 1564 blocks x 4 waves (6256 waves), points staged
// once, no merge phase, key-packed top-2, packed-fp32 dot pairs, x16
// replicated global accumulators, fused last-block finalize.

constexpr int KT = 64;
constexpr int P  = 2;
constexpr int NREP = 16;
constexpr float DIST_THRESH = 0.1f;
constexpr float W_DIST    = 0.05f;
constexpr float W_CHAMFER = 0.05f;
constexpr float W_SEP     = 0.0005f;
constexpr float PT_SENT = -1e18f;  // dummy-point sentinel (tail lanes)
constexpr float TG_SENT = -1e18f;  // invalid-target sentinel
constexpr float BIGF  = 3.0e38f;
constexpr float WBIAS = 16.0f;     // |t|^2 + WBIAS in T.w keeps valid keys > 0

typedef float f2 __attribute__((ext_vector_type(2)));

__device__ __forceinline__ unsigned umin_(unsigned a, unsigned b) { return a < b ? a : b; }
__device__ __forceinline__ unsigned umax_(unsigned a, unsigned b) { return a > b ? a : b; }

__device__ __forceinline__ f2 pk_fma(f2 a, f2 b, f2 c) {
#if __has_builtin(__builtin_elementwise_fma)
    return __builtin_elementwise_fma(a, b, c);
#else
    f2 r; r.x = fmaf(a.x, b.x, c.x); r.y = fmaf(a.y, b.y, c.y); return r;
#endif
}

// ws layout: [0,16384) g2p replicas rep*256+b*64+k (encode ~bits(g), init 0);
//            [16384,17408) sums replicas rep*16 + c*4 + b (float, init 0);
//            [17408,17412) last-block counter (init 0)
__global__ __launch_bounds__(256, 8)
void landmark_main(const float* __restrict__ C, const float* __restrict__ F,
                   const float* __restrict__ tC, const int* __restrict__ tF,
                   const int* __restrict__ classes, int n_classes, int N,
                   unsigned int* __restrict__ g2p_rep, float* __restrict__ sums_rep,
                   unsigned int* __restrict__ counter, float* __restrict__ out)
{
    __shared__ float4   tgtFull[KT];   // staged targets (-2t, |t|^2+WBIAS)
    __shared__ unsigned g2pLDS[KT];    // per-target min bits (float >= 0)
    __shared__ int      sIsLast;
    __shared__ float    lossb[4];

    const int tid   = threadIdx.x;
    const int lane  = tid & 63;
    const int wv    = tid >> 6;        // wave 0..3, each owns 128 points
    const int blk   = blockIdx.x;
    const int b     = blk & 3;
    const int chunk = blk >> 2;
    const int rep   = chunk & (NREP - 1);

    // Stage 64 targets: (-2tx,-2ty,-2tz, |t|^2+WBIAS), sentinel if invalid.
    if (tid < KT) {
        int f = tF[b * KT + tid];
        bool valid = false;
        for (int c = 0; c < n_classes; ++c) valid = valid || (f == classes[c]);
        float x = TG_SENT, y = TG_SENT, z = TG_SENT;
        if (valid) {
            x = tC[(b * KT + tid) * 3 + 0];
            y = tC[(b * KT + tid) * 3 + 1];
            z = tC[(b * KT + tid) * 3 + 2];
        }
        tgtFull[tid] = make_float4(-2.f * x, -2.f * y, -2.f * z,
                                   x * x + y * y + z * z + WBIAS);
        g2pLDS[tid] = 0x7F7FFFFFu;     // FLT_MAX bits
    }
    __syncthreads();

    const float*  Cb = C + (size_t)b * N * 3;
    const float4* Fb = (const float4*)(F + (size_t)b * N * 4);
    const int base = chunk * (64 * P * 4) + (wv << 7);   // wave owns 128 pts

    // ---- stage this wave's 128 points (loaded exactly once) ----
    f2 pcx[P], pcy[P], pcz[P];         // (raw coord, offset coord) packed pairs
    float ppm[P], ccm[P], f0[P];
    #pragma unroll
    for (int p = 0; p < P; ++p) {
        int n = base + p * 64 + lane;
        bool v = (n < N);
        int ni = v ? n : 0;
        float4 f4 = Fb[ni];
        float X = Cb[3 * ni + 0], Y = Cb[3 * ni + 1], Z = Cb[3 * ni + 2];
        // dummy points: coords -> sentinel; f0 -> 0.2 so dist term cancels.
        f0[p] = v ? f4.x : 2.0f * DIST_THRESH;
        if (!v) { X = PT_SENT; Y = PT_SENT; Z = PT_SENT; f4.y = f4.z = f4.w = 0.f; }
        float cxv = X + f4.y, cyv = Y + f4.z, czv = Z + f4.w;
        pcx[p] = (f2){X, cxv};
        pcy[p] = (f2){Y, cyv};
        pcz[p] = (f2){Z, czv};
        ppm[p] = fmaf(Z, Z, fmaf(Y, Y, X * X)) - WBIAS;
        ccm[p] = fmaf(czv, czv, fmaf(cyv, cyv, cxv * cxv)) - WBIAS;
    }

    // keyf = T.w - 2 p.t (= true pd2 - |p|^2 + WBIAS, > 0 for valid pairs)
    unsigned k1[P], k2[P];
    float lmin[P];
    #pragma unroll
    for (int p = 0; p < P; ++p) { k1[p] = 0xFFFFFFFFu; k2[p] = 0xFFFFFFFFu; lmin[p] = BIGF; }

    float g2p_home = BIGF;             // min ld^2 over this wave's pts, target #lane

    const int lx = lane ^ (wv << 4);   // phase-offset waves against each other
    #pragma unroll 8
    for (int i = 0; i < KT; ++i) {
        const int kk = lx ^ i;                        // bijection over 64 lanes
        const float4 T = tgtFull[kk];
        const unsigned tk = (unsigned)kk;
        const f2 Tx = {T.x, T.x}, Ty = {T.y, T.y}, Tz = {T.z, T.z}, Tw = {T.w, T.w};
        float av[P];
        #pragma unroll
        for (int p = 0; p < P; ++p) {
            f2 w2 = pk_fma(pcx[p], Tx, pk_fma(pcy[p], Ty, pk_fma(pcz[p], Tz, Tw)));
            unsigned key = (__float_as_uint(w2.x) & 0xFFFFFFC0u) | tk;
            unsigned hi = umax_(k1[p], key);
            k1[p] = umin_(k1[p], key);
            k2[p] = umin_(k2[p], hi);
            lmin[p] = fminf(lmin[p], w2.y);
            av[p] = w2.y + ccm[p];                    // true ld2 for cross-p compare
        }
        float dl = fmaxf(fminf(av[0], av[1]), 0.f);
        // Route dl to its target's home lane: lane d pulls from lane d^(wv<<4)^i,
        // i.e. the unique lane whose kk == d this iteration. bpermute addr = kk<<2.
        int got = __builtin_amdgcn_ds_bpermute(kk << 2, __float_as_int(dl));
        g2p_home = fminf(g2p_home, __int_as_float(got));
    }

    // Combine the 4 waves' per-target minima: ONE LDS atomic per wave.
    atomicMin(&g2pLDS[lane], __float_as_uint(g2p_home));

    // ---- per-wave epilogue (no merge: each wave saw all 64 targets) ----
    float dist_acc = 0.f, p2g_acc = 0.f, sep_acc = 0.f;
    #pragma unroll
    for (int p = 0; p < P; ++p) {
        unsigned m1 = k1[p], m2 = k2[p];
        float lm = lmin[p];
        float keyf1 = __uint_as_float(m1 & 0xFFFFFFC0u);
        float mind = sqrtf(fmaxf(keyf1 + ppm[p], 0.f));
        bool pm = mind < DIST_THRESH;                // false for dummy (ppm huge)
        float tgtv = fminf(mind, 2.0f * DIST_THRESH);
        float diff = f0[p] - tgtv;
        float ad = fabsf(diff);
        dist_acc += (ad < 1.0f) ? 0.5f * diff * diff : (ad - 0.5f);
        if (pm) {
            p2g_acc += fmaxf(lm + ccm[p], 0.f);
            int i1 = (int)(m1 & 63u), i2 = (int)(m2 & 63u);
            float4 T1 = tgtFull[i1], T2 = tgtFull[i2];
            float cxv = pcx[p].y, cyv = pcy[p].y, czv = pcz[p].y;
            float l1sq = fmaf(cxv, T1.x, fmaf(cyv, T1.y, fmaf(czv, T1.z, T1.w))) + ccm[p];
            float l2sq = fmaf(cxv, T2.x, fmaf(cyv, T2.y, fmaf(czv, T2.z, T2.w))) + ccm[p];
            sep_acc += sqrtf(fmaxf(l1sq, 0.f) / fmaxf(l2sq, 1e-30f));
        }
    }

    float v0 = dist_acc, v1 = p2g_acc, v2 = sep_acc;
    #pragma unroll
    for (int o = 32; o > 0; o >>= 1) {
        v0 += __shfl_down(v0, o, 64);
        v1 += __shfl_down(v1, o, 64);
        v2 += __shfl_down(v2, o, 64);
    }
    if (lane == 0) {
        float* sb = sums_rep + rep * 16 + b;
        atomicAdd(sb + 0, v0);
        atomicAdd(sb + 4, v1);
        atomicAdd(sb + 8, v2);
    }

    __syncthreads();   // all 4 waves' g2pLDS combine complete
    if (tid < KT)
        atomicMax(&g2p_rep[rep * 256 + b * 64 + tid], ~g2pLDS[tid]);

    // ---- last-block-done fused finalize ----
    __threadfence();   // release this block's atomics before counter bump
    __syncthreads();
    if (tid == 0)
        sIsLast = (atomicAdd(counter, 1u) == (unsigned)(gridDim.x - 1));
    __syncthreads();
    if (!sIsLast) return;

    // Last block: all other blocks' atomics are globally visible (they fenced
    // before bumping). Read via atomic ops to dodge any stale-L1/L2 path.
    const int b2 = tid >> 6, k = tid & 63;
    int fk = tF[b2 * KT + k];
    bool valid = false;
    for (int c = 0; c < n_classes; ++c) valid = valid || (fk == classes[c]);

    unsigned enc = 0;
    for (int r = 0; r < NREP; ++r)
        enc = umax_(enc, atomicMax(&g2p_rep[r * 256 + b2 * 64 + k], 0u));
    float g  = valid ? __uint_as_float(~enc) : 0.f;
    float nv = valid ? 1.f : 0.f;

    #pragma unroll
    for (int o = 32; o > 0; o >>= 1) {
        g  += __shfl_down(g, o, 64);
        nv += __shfl_down(nv, o, 64);
    }
    if (k == 0) {
        float sd = 0.f, sp = 0.f, ss = 0.f;
        for (int r = 0; r < NREP; ++r) {
            sd += atomicAdd(&sums_rep[r * 16 + 0 + b2], 0.f);
            sp += atomicAdd(&sums_rep[r * 16 + 4 + b2], 0.f);
            ss += atomicAdd(&sums_rep[r * 16 + 8 + b2], 0.f);
        }
        float sep = (nv >= 2.f) ? ss : 0.f;
        lossb[b2] = W_DIST * sd + W_CHAMFER * (sp + g) + W_SEP * sep;
    }
    __syncthreads();
    if (tid == 0)
        out[0] = (lossb[0] + lossb[1] + lossb[2] + lossb[3]) * 0.25f;
}

extern "C" void kernel_launch(void* const* d_in, const int* in_sizes, int n_in,
                              void* d_out, int out_size, void* d_ws, size_t ws_size,
                              hipStream_t stream)
{
    const float* C       = (const float*)d_in[0];   // (B,N,3)
    const float* F       = (const float*)d_in[1];   // (B,N,4)
    const float* tC      = (const float*)d_in[2];   // (B,K,3)
    const int*   tF      = (const int*)d_in[3];     // (B,K)
    const int*   classes = (const int*)d_in[4];     // (6,)
    const int n_classes = in_sizes[4];
    const int B = 4;
    const int N = in_sizes[0] / (3 * B);            // 200000

    unsigned int* g2p_rep  = (unsigned int*)d_ws;
    float*        sums_rep = (float*)((char*)d_ws + NREP * 256 * 4);
    unsigned int* counter  = (unsigned int*)((char*)d_ws + NREP * 256 * 4 + NREP * 16 * 4);

    hipMemsetAsync(d_ws, 0, NREP * 256 * 4 + NREP * 16 * 4 + 4, stream);

    const int cpb = (N + 64 * P * 4 - 1) / (64 * P * 4);  // 391 chunks per batch
    landmark_main<<<cpb * 4, 256, 0, stream>>>(C, F, tC, tF, classes, n_classes,
                                               N, g2p_rep, sums_rep, counter,
                                               (float*)d_out);
}

// Round 4
// 148.462 us; speedup vs baseline: 1.1981x; 1.1981x over previous
//
#include <hip/hip_runtime.h>

// LandmarkLoss, round 15. B=4, N=200000, K=64.
// Rounds 11-14 normalized by per-CU wave-iterations: every variant costs
// ~100-200 cyc per inner-loop iteration (1 ds_read + 1 ds routing op each),
// while the whole kernel's VALU floor is ~7us (VALUBusy 13-21% everywhere).
// Duration tracks ITERATION count + DS latency exposure, not pair count.
// R15: P=8 points/lane x K-split (wave owns 32 targets, R11's scheme) in
// 128-thr blocks -> 32 iterations of ~85 VALU instrs each: DS ops per pair
// halve vs R11 (0.25), and each iteration self-hides its DS latency under
// ~170cyc of independent VALU, decoupling from occupancy (12 waves/CU).
// Carried: fire-and-forget ds_min (R14 proved bpermute worse: +return
// latency on same pipe), phase-disjoint rotation tk = (l31^(hi<<4)|h*32)^i
// (32-lane phases hit distinct words), packed-fp32 dot pairs, key-packed
// top-2 + one-time cross-wave merge, x16 replicated global accumulators,
// fused last-block finalize. Both waves load the same 512 points (2nd wave
// L1-hits; FETCH_SIZE unchanged) -- cheaper than an LDS exchange.

constexpr int KT = 64;
constexpr int P  = 8;
constexpr int NREP = 16;
constexpr float DIST_THRESH = 0.1f;
constexpr float W_DIST    = 0.05f;
constexpr float W_CHAMFER = 0.05f;
constexpr float W_SEP     = 0.0005f;
constexpr float PT_SENT = -1e18f;  // dummy-point sentinel (tail lanes)
constexpr float TG_SENT = -1e18f;  // invalid-target sentinel
constexpr float BIGF  = 3.0e38f;
constexpr float WBIAS = 16.0f;     // |t|^2 + WBIAS in T.w keeps valid keys > 0

typedef float f2 __attribute__((ext_vector_type(2)));

__device__ __forceinline__ unsigned umin_(unsigned a, unsigned b) { return a < b ? a : b; }
__device__ __forceinline__ unsigned umax_(unsigned a, unsigned b) { return a > b ? a : b; }

__device__ __forceinline__ f2 pk_fma(f2 a, f2 b, f2 c) {
#if __has_builtin(__builtin_elementwise_fma)
    return __builtin_elementwise_fma(a, b, c);
#else
    f2 r; r.x = fmaf(a.x, b.x, c.x); r.y = fmaf(a.y, b.y, c.y); return r;
#endif
}

// ws layout: [0,16384) g2p replicas rep*256+b*64+k (encode ~bits(g), init 0);
//            [16384,17408) sums replicas rep*16 + c*4 + b (float, init 0);
//            [17408,17412) last-block counter (init 0)
__global__ __launch_bounds__(128, 3)
void landmark_main(const float* __restrict__ C, const float* __restrict__ F,
                   const float* __restrict__ tC, const int* __restrict__ tF,
                   const int* __restrict__ classes, int n_classes, int N,
                   unsigned int* __restrict__ g2p_rep, float* __restrict__ sums_rep,
                   unsigned int* __restrict__ counter, float* __restrict__ out)
{
    __shared__ float4   tgtFull[KT];   // staged targets (-2t, |t|^2+WBIAS)
    __shared__ unsigned g2pLDS[KT];    // per-target min bits (float >= 0)
    __shared__ uint4    mK1[128];      // wave A -> B merge buffers (64 lanes x 8)
    __shared__ uint4    mK2[128];
    __shared__ float4   mLM[128];
    __shared__ int      sIsLast;
    __shared__ float    lossb[4];

    const int tid   = threadIdx.x;
    const int lane  = tid & 63;
    const int h     = tid >> 6;        // wave: 0 -> targets [0,32), 1 -> [32,64)
    const int l31   = lane & 31;
    const int hi5   = lane >> 5;       // within-wave 32-lane phase
    const int blk   = blockIdx.x;
    const int b     = blk & 3;
    const int chunk = blk >> 2;
    const int rep   = chunk & (NREP - 1);

    // Stage 64 targets: (-2tx,-2ty,-2tz, |t|^2+WBIAS), sentinel if invalid.
    if (tid < KT) {
        int f = tF[b * KT + tid];
        bool valid = false;
        for (int c = 0; c < n_classes; ++c) valid = valid || (f == classes[c]);
        float x = TG_SENT, y = TG_SENT, z = TG_SENT;
        if (valid) {
            x = tC[(b * KT + tid) * 3 + 0];
            y = tC[(b * KT + tid) * 3 + 1];
            z = tC[(b * KT + tid) * 3 + 2];
        }
        tgtFull[tid] = make_float4(-2.f * x, -2.f * y, -2.f * z,
                                   x * x + y * y + z * z + WBIAS);
        g2pLDS[tid] = 0x7F7FFFFFu;     // FLT_MAX bits
    }
    __syncthreads();

    const float*  Cb = C + (size_t)b * N * 3;
    const float4* Fb = (const float4*)(F + (size_t)b * N * 4);
    const int base = chunk * (64 * P);   // block covers 512 points

    // ---- stage 512 points, 8/lane (both waves stage the same set; the
    //      second wave's loads are L1 hits) ----
    f2 pcx[P], pcy[P], pcz[P];         // (raw coord, offset coord) packed pairs
    float ppm[P], ccm[P], f0[P];
    #pragma unroll
    for (int p = 0; p < P; ++p) {
        int n = base + p * 64 + lane;
        bool v = (n < N);
        int ni = v ? n : 0;
        float4 f4 = Fb[ni];
        float X = Cb[3 * ni + 0], Y = Cb[3 * ni + 1], Z = Cb[3 * ni + 2];
        // dummy points: coords -> sentinel; f0 -> 0.2 so dist term cancels.
        f0[p] = v ? f4.x : 2.0f * DIST_THRESH;
        if (!v) { X = PT_SENT; Y = PT_SENT; Z = PT_SENT; f4.y = f4.z = f4.w = 0.f; }
        float cxv = X + f4.y, cyv = Y + f4.z, czv = Z + f4.w;
        pcx[p] = (f2){X, cxv};
        pcy[p] = (f2){Y, cyv};
        pcz[p] = (f2){Z, czv};
        ppm[p] = fmaf(Z, Z, fmaf(Y, Y, X * X)) - WBIAS;
        ccm[p] = fmaf(czv, czv, fmaf(cyv, cyv, cxv * cxv)) - WBIAS;
    }

    // keyf = T.w - 2 p.t (= true pd2 - |p|^2 + WBIAS, > 0 for valid pairs)
    unsigned k1[P], k2[P];
    float lmin[P];
    #pragma unroll
    for (int p = 0; p < P; ++p) { k1[p] = 0xFFFFFFFFu; k2[p] = 0xFFFFFFFFu; lmin[p] = BIGF; }

    // Rotation: tk = tkb ^ i. Within each 32-lane phase the tk values are
    // distinct, so the phase's ds_min ops hit 32 distinct words.
    const unsigned tkb = (unsigned)((l31 ^ (hi5 << 4)) | (h << 5));
    #pragma unroll 4
    for (int i = 0; i < 32; ++i) {
        const unsigned tk = tkb ^ (unsigned)i;        // this wave's target half
        const float4 T = tgtFull[tk];
        const f2 Tx = {T.x, T.x}, Ty = {T.y, T.y}, Tz = {T.z, T.z}, Tw = {T.w, T.w};
        float av[P];
        #pragma unroll
        for (int p = 0; p < P; ++p) {
            f2 w2 = pk_fma(pcx[p], Tx, pk_fma(pcy[p], Ty, pk_fma(pcz[p], Tz, Tw)));
            unsigned key = (__float_as_uint(w2.x) & 0xFFFFFFC0u) | tk;
            unsigned hi = umax_(k1[p], key);
            k1[p] = umin_(k1[p], key);
            k2[p] = umin_(k2[p], hi);
            lmin[p] = fminf(lmin[p], w2.y);
            av[p] = w2.y + ccm[p];                    // true ld2 for cross-p compare
        }
        float m01 = fminf(av[0], av[1]), m23 = fminf(av[2], av[3]);
        float m45 = fminf(av[4], av[5]), m67 = fminf(av[6], av[7]);
        float dl = fmaxf(fminf(fminf(m01, m23), fminf(m45, m67)), 0.f);
        atomicMin(&g2pLDS[tk], __float_as_uint(dl)); // ds_min_u32, no return
    }

    // ---- wave A publishes its per-point top-2/lmin for the merge ----
    if (h == 0) {
        mK1[lane * 2 + 0] = make_uint4(k1[0], k1[1], k1[2], k1[3]);
        mK1[lane * 2 + 1] = make_uint4(k1[4], k1[5], k1[6], k1[7]);
        mK2[lane * 2 + 0] = make_uint4(k2[0], k2[1], k2[2], k2[3]);
        mK2[lane * 2 + 1] = make_uint4(k2[4], k2[5], k2[6], k2[7]);
        mLM[lane * 2 + 0] = make_float4(lmin[0], lmin[1], lmin[2], lmin[3]);
        mLM[lane * 2 + 1] = make_float4(lmin[4], lmin[5], lmin[6], lmin[7]);
    }
    __syncthreads();   // covers ds_min completion + merge publish

    if (h == 0) {
        // per-target g2p -> replicated global (wave A, one lane per target).
        // g2pLDS holds bits(g), g>=0; ~bits monotone decreasing -> atomicMax == min.
        atomicMax(&g2p_rep[rep * 256 + b * 64 + lane], ~g2pLDS[lane]);
    } else {
        // ---- merge halves + epilogue (wave B only; same point registers) ----
        uint4 A1a = mK1[lane * 2], A1b = mK1[lane * 2 + 1];
        uint4 A2a = mK2[lane * 2], A2b = mK2[lane * 2 + 1];
        float4 ALa = mLM[lane * 2], ALb = mLM[lane * 2 + 1];
        const unsigned a1v[P] = {A1a.x, A1a.y, A1a.z, A1a.w, A1b.x, A1b.y, A1b.z, A1b.w};
        const unsigned a2v[P] = {A2a.x, A2a.y, A2a.z, A2a.w, A2b.x, A2b.y, A2b.z, A2b.w};
        const float    alv[P] = {ALa.x, ALa.y, ALa.z, ALa.w, ALb.x, ALb.y, ALb.z, ALb.w};

        float dist_acc = 0.f, p2g_acc = 0.f, sep_acc = 0.f;
        #pragma unroll
        for (int p = 0; p < P; ++p) {
            unsigned m1 = umin_(a1v[p], k1[p]);
            unsigned m2 = umin_(umax_(a1v[p], k1[p]), umin_(a2v[p], k2[p]));
            float lm = fminf(alv[p], lmin[p]);
            float keyf1 = __uint_as_float(m1 & 0xFFFFFFC0u);
            float mind = sqrtf(fmaxf(keyf1 + ppm[p], 0.f));
            bool pm = mind < DIST_THRESH;            // false for dummy (ppm huge)
            float tgtv = fminf(mind, 2.0f * DIST_THRESH);
            float diff = f0[p] - tgtv;
            float ad = fabsf(diff);
            dist_acc += (ad < 1.0f) ? 0.5f * diff * diff : (ad - 0.5f);
            if (pm) {
                p2g_acc += fmaxf(lm + ccm[p], 0.f);
                int i1 = (int)(m1 & 63u), i2 = (int)(m2 & 63u);
                float4 T1 = tgtFull[i1], T2 = tgtFull[i2];
                float cxv = pcx[p].y, cyv = pcy[p].y, czv = pcz[p].y;
                float l1sq = fmaf(cxv, T1.x, fmaf(cyv, T1.y, fmaf(czv, T1.z, T1.w))) + ccm[p];
                float l2sq = fmaf(cxv, T2.x, fmaf(cyv, T2.y, fmaf(czv, T2.z, T2.w))) + ccm[p];
                sep_acc += sqrtf(fmaxf(l1sq, 0.f) / fmaxf(l2sq, 1e-30f));
            }
        }

        float v0 = dist_acc, v1 = p2g_acc, v2 = sep_acc;
        #pragma unroll
        for (int o = 32; o > 0; o >>= 1) {
            v0 += __shfl_down(v0, o, 64);
            v1 += __shfl_down(v1, o, 64);
            v2 += __shfl_down(v2, o, 64);
        }
        if (lane == 0) {
            float* sb = sums_rep + rep * 16 + b;
            atomicAdd(sb + 0, v0);
            atomicAdd(sb + 4, v1);
            atomicAdd(sb + 8, v2);
        }
    }

    // ---- last-block-done fused finalize ----
    __threadfence();   // release this block's atomics before counter bump
    __syncthreads();
    if (tid == 0)
        sIsLast = (atomicAdd(counter, 1u) == (unsigned)(gridDim.x - 1));
    __syncthreads();
    if (!sIsLast) return;

    // Last block (128 threads): each wave handles 2 batches serially.
    // Read via atomic ops to dodge any stale-L1/L2 path.
    for (int b2 = h; b2 < 4; b2 += 2) {
        const int k = lane;
        int fk = tF[b2 * KT + k];
        bool valid = false;
        for (int c = 0; c < n_classes; ++c) valid = valid || (fk == classes[c]);

        unsigned enc = 0;
        for (int r = 0; r < NREP; ++r)
            enc = umax_(enc, atomicMax(&g2p_rep[r * 256 + b2 * 64 + k], 0u));
        float g  = valid ? __uint_as_float(~enc) : 0.f;
        float nv = valid ? 1.f : 0.f;

        #pragma unroll
        for (int o = 32; o > 0; o >>= 1) {
            g  += __shfl_down(g, o, 64);
            nv += __shfl_down(nv, o, 64);
        }
        if (k == 0) {
            float sd = 0.f, sp = 0.f, ss = 0.f;
            for (int r = 0; r < NREP; ++r) {
                sd += atomicAdd(&sums_rep[r * 16 + 0 + b2], 0.f);
                sp += atomicAdd(&sums_rep[r * 16 + 4 + b2], 0.f);
                ss += atomicAdd(&sums_rep[r * 16 + 8 + b2], 0.f);
            }
            float sep = (nv >= 2.f) ? ss : 0.f;
            lossb[b2] = W_DIST * sd + W_CHAMFER * (sp + g) + W_SEP * sep;
        }
    }
    __syncthreads();
    if (tid == 0)
        out[0] = (lossb[0] + lossb[1] + lossb[2] + lossb[3]) * 0.25f;
}

extern "C" void kernel_launch(void* const* d_in, const int* in_sizes, int n_in,
                              void* d_out, int out_size, void* d_ws, size_t ws_size,
                              hipStream_t stream)
{
    const float* C       = (const float*)d_in[0];   // (B,N,3)
    const float* F       = (const float*)d_in[1];   // (B,N,4)
    const float* tC      = (const float*)d_in[2];   // (B,K,3)
    const int*   tF      = (const int*)d_in[3];     // (B,K)
    const int*   classes = (const int*)d_in[4];     // (6,)
    const int n_classes = in_sizes[4];
    const int B = 4;
    const int N = in_sizes[0] / (3 * B);            // 200000

    unsigned int* g2p_rep  = (unsigned int*)d_ws;
    float*        sums_rep = (float*)((char*)d_ws + NREP * 256 * 4);
    unsigned int* counter  = (unsigned int*)((char*)d_ws + NREP * 256 * 4 + NREP * 16 * 4);

    hipMemsetAsync(d_ws, 0, NREP * 256 * 4 + NREP * 16 * 4 + 4, stream);

    const int cpb = (N + 64 * P - 1) / (64 * P);    // 391 chunks per batch
    landmark_main<<<cpb * 4, 128, 0, stream>>>(C, F, tC, tF, classes, n_classes,
                                               N, g2p_rep, sums_rep, counter,
                                               (float*)d_out);
}

// Round 5
// 103.581 us; speedup vs baseline: 1.7172x; 1.4333x over previous
//
#include <hip/hip_runtime.h>

// LandmarkLoss, round 16. B=4, N=200000, K=64.
// R12-R15 post-mortem: fitting dur ~ base_work + c*nblocks across rounds gives
// c ~ 45ns/block -- the per-block __threadfence() (device-scope fence = L2
// writeback serialized at TCC) + same-address counter atomic introduced by the
// fused finalize in R12. R11 (no fence) was 32us at 3128 blocks; R13/R15
// (1564 blocks, fenced) paid ~70us of pure fence tax. Every structural theory
// in R12-R15 was confounded by this term.
// R16 = R15's body (lowest base_work: P=8, K-split, 0.25 DS ops/pair,
// ~15us fence-adjusted) + two-dispatch scheme (fence/counter DELETED; kernel
// boundary provides cross-XCD visibility, as R11 proved) + SoA merge buffers
// (R15's mK1[lane*2] put lanes 32B apart -> 416K conflict-cycles; SoA arrays
// indexed by lane make the ds_write_b128s conflict-free, back to ~13K).
// Carried: fire-and-forget ds_min, phase-disjoint rotation, packed-fp32 dot
// pairs, key-packed top-2 + one-time cross-wave merge, x16 replicated global
// accumulators, R11's proven separate finalize kernel.

constexpr int KT = 64;
constexpr int P  = 8;
constexpr int NREP = 16;
constexpr float DIST_THRESH = 0.1f;
constexpr float W_DIST    = 0.05f;
constexpr float W_CHAMFER = 0.05f;
constexpr float W_SEP     = 0.0005f;
constexpr float PT_SENT = -1e18f;  // dummy-point sentinel (tail lanes)
constexpr float TG_SENT = -1e18f;  // invalid-target sentinel
constexpr float BIGF  = 3.0e38f;
constexpr float WBIAS = 16.0f;     // |t|^2 + WBIAS in T.w keeps valid keys > 0

typedef float f2 __attribute__((ext_vector_type(2)));

__device__ __forceinline__ unsigned umin_(unsigned a, unsigned b) { return a < b ? a : b; }
__device__ __forceinline__ unsigned umax_(unsigned a, unsigned b) { return a > b ? a : b; }

__device__ __forceinline__ f2 pk_fma(f2 a, f2 b, f2 c) {
#if __has_builtin(__builtin_elementwise_fma)
    return __builtin_elementwise_fma(a, b, c);
#else
    f2 r; r.x = fmaf(a.x, b.x, c.x); r.y = fmaf(a.y, b.y, c.y); return r;
#endif
}

// ws layout: [0,16384) g2p replicas rep*256+b*64+k (encode ~bits(g), init 0);
//            [16384,17408) sums replicas rep*16 + c*4 + b (float, init 0)
__global__ __launch_bounds__(128, 3)
void landmark_main(const float* __restrict__ C, const float* __restrict__ F,
                   const float* __restrict__ tC, const int* __restrict__ tF,
                   const int* __restrict__ classes, int n_classes, int N,
                   unsigned int* __restrict__ g2p_rep, float* __restrict__ sums_rep)
{
    __shared__ float4   tgtFull[KT];   // staged targets (-2t, |t|^2+WBIAS)
    __shared__ unsigned g2pLDS[KT];    // per-target min bits (float >= 0)
    __shared__ uint4    mK1a[64], mK1b[64];   // SoA merge buffers: lane-indexed
    __shared__ uint4    mK2a[64], mK2b[64];   // (16B/lane stride -> conflict-free
    __shared__ float4   mLMa[64], mLMb[64];   //  ds_write_b128)

    const int tid   = threadIdx.x;
    const int lane  = tid & 63;
    const int h     = tid >> 6;        // wave: 0 -> targets [0,32), 1 -> [32,64)
    const int l31   = lane & 31;
    const int hi5   = lane >> 5;       // within-wave 32-lane phase
    const int blk   = blockIdx.x;
    const int b     = blk & 3;
    const int chunk = blk >> 2;
    const int rep   = chunk & (NREP - 1);

    // Stage 64 targets: (-2tx,-2ty,-2tz, |t|^2+WBIAS), sentinel if invalid.
    if (tid < KT) {
        int f = tF[b * KT + tid];
        bool valid = false;
        for (int c = 0; c < n_classes; ++c) valid = valid || (f == classes[c]);
        float x = TG_SENT, y = TG_SENT, z = TG_SENT;
        if (valid) {
            x = tC[(b * KT + tid) * 3 + 0];
            y = tC[(b * KT + tid) * 3 + 1];
            z = tC[(b * KT + tid) * 3 + 2];
        }
        tgtFull[tid] = make_float4(-2.f * x, -2.f * y, -2.f * z,
                                   x * x + y * y + z * z + WBIAS);
        g2pLDS[tid] = 0x7F7FFFFFu;     // FLT_MAX bits
    }
    __syncthreads();

    const float*  Cb = C + (size_t)b * N * 3;
    const float4* Fb = (const float4*)(F + (size_t)b * N * 4);
    const int base = chunk * (64 * P);   // block covers 512 points

    // ---- stage 512 points, 8/lane (both waves stage the same set; the
    //      second wave's loads are L1 hits) ----
    f2 pcx[P], pcy[P], pcz[P];         // (raw coord, offset coord) packed pairs
    float ppm[P], ccm[P], f0[P];
    #pragma unroll
    for (int p = 0; p < P; ++p) {
        int n = base + p * 64 + lane;
        bool v = (n < N);
        int ni = v ? n : 0;
        float4 f4 = Fb[ni];
        float X = Cb[3 * ni + 0], Y = Cb[3 * ni + 1], Z = Cb[3 * ni + 2];
        // dummy points: coords -> sentinel; f0 -> 0.2 so dist term cancels.
        f0[p] = v ? f4.x : 2.0f * DIST_THRESH;
        if (!v) { X = PT_SENT; Y = PT_SENT; Z = PT_SENT; f4.y = f4.z = f4.w = 0.f; }
        float cxv = X + f4.y, cyv = Y + f4.z, czv = Z + f4.w;
        pcx[p] = (f2){X, cxv};
        pcy[p] = (f2){Y, cyv};
        pcz[p] = (f2){Z, czv};
        ppm[p] = fmaf(Z, Z, fmaf(Y, Y, X * X)) - WBIAS;
        ccm[p] = fmaf(czv, czv, fmaf(cyv, cyv, cxv * cxv)) - WBIAS;
    }

    // keyf = T.w - 2 p.t (= true pd2 - |p|^2 + WBIAS, > 0 for valid pairs)
    unsigned k1[P], k2[P];
    float lmin[P];
    #pragma unroll
    for (int p = 0; p < P; ++p) { k1[p] = 0xFFFFFFFFu; k2[p] = 0xFFFFFFFFu; lmin[p] = BIGF; }

    // Rotation: tk = tkb ^ i. Within each 32-lane phase the tk values are
    // distinct, so the phase's ds_min ops hit 32 distinct words.
    const unsigned tkb = (unsigned)((l31 ^ (hi5 << 4)) | (h << 5));
    #pragma unroll 4
    for (int i = 0; i < 32; ++i) {
        const unsigned tk = tkb ^ (unsigned)i;        // this wave's target half
        const float4 T = tgtFull[tk];
        const f2 Tx = {T.x, T.x}, Ty = {T.y, T.y}, Tz = {T.z, T.z}, Tw = {T.w, T.w};
        float av[P];
        #pragma unroll
        for (int p = 0; p < P; ++p) {
            f2 w2 = pk_fma(pcx[p], Tx, pk_fma(pcy[p], Ty, pk_fma(pcz[p], Tz, Tw)));
            unsigned key = (__float_as_uint(w2.x) & 0xFFFFFFC0u) | tk;
            unsigned hi = umax_(k1[p], key);
            k1[p] = umin_(k1[p], key);
            k2[p] = umin_(k2[p], hi);
            lmin[p] = fminf(lmin[p], w2.y);
            av[p] = w2.y + ccm[p];                    // true ld2 for cross-p compare
        }
        float m01 = fminf(av[0], av[1]), m23 = fminf(av[2], av[3]);
        float m45 = fminf(av[4], av[5]), m67 = fminf(av[6], av[7]);
        float dl = fmaxf(fminf(fminf(m01, m23), fminf(m45, m67)), 0.f);
        atomicMin(&g2pLDS[tk], __float_as_uint(dl)); // ds_min_u32, no return
    }

    // ---- wave A publishes its per-point top-2/lmin for the merge ----
    if (h == 0) {
        mK1a[lane] = make_uint4(k1[0], k1[1], k1[2], k1[3]);
        mK1b[lane] = make_uint4(k1[4], k1[5], k1[6], k1[7]);
        mK2a[lane] = make_uint4(k2[0], k2[1], k2[2], k2[3]);
        mK2b[lane] = make_uint4(k2[4], k2[5], k2[6], k2[7]);
        mLMa[lane] = make_float4(lmin[0], lmin[1], lmin[2], lmin[3]);
        mLMb[lane] = make_float4(lmin[4], lmin[5], lmin[6], lmin[7]);
    }
    __syncthreads();   // covers ds_min completion + merge publish

    if (h == 0) {
        // per-target g2p -> replicated global (wave A, one lane per target).
        // g2pLDS holds bits(g), g>=0; ~bits monotone decreasing -> atomicMax == min.
        atomicMax(&g2p_rep[rep * 256 + b * 64 + lane], ~g2pLDS[lane]);
    } else {
        // ---- merge halves + epilogue (wave B only; same point registers) ----
        uint4 A1a = mK1a[lane], A1b = mK1b[lane];
        uint4 A2a = mK2a[lane], A2b = mK2b[lane];
        float4 ALa = mLMa[lane], ALb = mLMb[lane];
        const unsigned a1v[P] = {A1a.x, A1a.y, A1a.z, A1a.w, A1b.x, A1b.y, A1b.z, A1b.w};
        const unsigned a2v[P] = {A2a.x, A2a.y, A2a.z, A2a.w, A2b.x, A2b.y, A2b.z, A2b.w};
        const float    alv[P] = {ALa.x, ALa.y, ALa.z, ALa.w, ALb.x, ALb.y, ALb.z, ALb.w};

        float dist_acc = 0.f, p2g_acc = 0.f, sep_acc = 0.f;
        #pragma unroll
        for (int p = 0; p < P; ++p) {
            unsigned m1 = umin_(a1v[p], k1[p]);
            unsigned m2 = umin_(umax_(a1v[p], k1[p]), umin_(a2v[p], k2[p]));
            float lm = fminf(alv[p], lmin[p]);
            float keyf1 = __uint_as_float(m1 & 0xFFFFFFC0u);
            float mind = sqrtf(fmaxf(keyf1 + ppm[p], 0.f));
            bool pm = mind < DIST_THRESH;            // false for dummy (ppm huge)
            float tgtv = fminf(mind, 2.0f * DIST_THRESH);
            float diff = f0[p] - tgtv;
            float ad = fabsf(diff);
            dist_acc += (ad < 1.0f) ? 0.5f * diff * diff : (ad - 0.5f);
            if (pm) {
                p2g_acc += fmaxf(lm + ccm[p], 0.f);
                int i1 = (int)(m1 & 63u), i2 = (int)(m2 & 63u);
                float4 T1 = tgtFull[i1], T2 = tgtFull[i2];
                float cxv = pcx[p].y, cyv = pcy[p].y, czv = pcz[p].y;
                float l1sq = fmaf(cxv, T1.x, fmaf(cyv, T1.y, fmaf(czv, T1.z, T1.w))) + ccm[p];
                float l2sq = fmaf(cxv, T2.x, fmaf(cyv, T2.y, fmaf(czv, T2.z, T2.w))) + ccm[p];
                sep_acc += sqrtf(fmaxf(l1sq, 0.f) / fmaxf(l2sq, 1e-30f));
            }
        }

        float v0 = dist_acc, v1 = p2g_acc, v2 = sep_acc;
        #pragma unroll
        for (int o = 32; o > 0; o >>= 1) {
            v0 += __shfl_down(v0, o, 64);
            v1 += __shfl_down(v1, o, 64);
            v2 += __shfl_down(v2, o, 64);
        }
        if (lane == 0) {
            float* sb = sums_rep + rep * 16 + b;
            atomicAdd(sb + 0, v0);
            atomicAdd(sb + 4, v1);
            atomicAdd(sb + 8, v2);
        }
    }
}

__global__ void landmark_finalize(const int* __restrict__ tF, const int* __restrict__ classes,
                                  int n_classes, const unsigned int* __restrict__ g2p_rep,
                                  const float* __restrict__ sums_rep, float* __restrict__ out)
{
    __shared__ float lossb[4];
    const int tid = threadIdx.x;          // 256 threads
    const int b = tid >> 6, k = tid & 63;

    int f = tF[b * KT + k];
    bool valid = false;
    for (int c = 0; c < n_classes; ++c) valid = valid || (f == classes[c]);

    unsigned enc = 0;
    for (int r = 0; r < NREP; ++r) enc = umax_(enc, g2p_rep[r * 256 + b * 64 + k]);
    float g  = valid ? __uint_as_float(~enc) : 0.f;
    float nv = valid ? 1.f : 0.f;

    #pragma unroll
    for (int o = 32; o > 0; o >>= 1) {
        g  += __shfl_down(g, o, 64);
        nv += __shfl_down(nv, o, 64);
    }
    if (k == 0) {
        float sd = 0.f, sp = 0.f, ss = 0.f;
        for (int r = 0; r < NREP; ++r) {
            sd += sums_rep[r * 16 + 0 + b];
            sp += sums_rep[r * 16 + 4 + b];
            ss += sums_rep[r * 16 + 8 + b];
        }
        float sep = (nv >= 2.f) ? ss : 0.f;
        lossb[b] = W_DIST * sd + W_CHAMFER * (sp + g) + W_SEP * sep;
    }
    __syncthreads();
    if (tid == 0)
        out[0] = (lossb[0] + lossb[1] + lossb[2] + lossb[3]) * 0.25f;
}

extern "C" void kernel_launch(void* const* d_in, const int* in_sizes, int n_in,
                              void* d_out, int out_size, void* d_ws, size_t ws_size,
                              hipStream_t stream)
{
    const float* C       = (const float*)d_in[0];   // (B,N,3)
    const float* F       = (const float*)d_in[1];   // (B,N,4)
    const float* tC      = (const float*)d_in[2];   // (B,K,3)
    const int*   tF      = (const int*)d_in[3];     // (B,K)
    const int*   classes = (const int*)d_in[4];     // (6,)
    const int n_classes = in_sizes[4];
    const int B = 4;
    const int N = in_sizes[0] / (3 * B);            // 200000

    unsigned int* g2p_rep  = (unsigned int*)d_ws;
    float*        sums_rep = (float*)((char*)d_ws + NREP * 256 * 4);

    hipMemsetAsync(d_ws, 0, NREP * 256 * 4 + NREP * 16 * 4, stream);

    const int cpb = (N + 64 * P - 1) / (64 * P);    // 391 chunks per batch
    landmark_main<<<cpb * 4, 128, 0, stream>>>(C, F, tC, tF, classes, n_classes,
                                               N, g2p_rep, sums_rep);
    landmark_finalize<<<1, 256, 0, stream>>>(tF, classes, n_classes, g2p_rep,
                                             sums_rep, (float*)d_out);
}

// Round 6
// 101.595 us; speedup vs baseline: 1.7507x; 1.0196x over previous
//
#include <hip/hip_runtime.h>

// LandmarkLoss, round 17. B=4, N=200000, K=64.
// R16 calibration vs R0: main_R16 ~36us vs R11's 32 despite half the
// iterations/DS-ops -> iteration-count and DS-op theories dead. VALU floor is
// ~7us; main is ~80% LATENCY EXPOSURE (per-block serial stage->compute), and
// every round that reduced concurrent staging streams lost. R17 keeps R11's
// proven-best body VERBATIM (P=4, 2-wave K-split 32/32, lane-indexed merge
// buffers) and adds chunk-PAIR pipelining: issue chunk-1's raw global loads
// before chunk-0's 32-iter loop (~1500cyc VALU covers ~900cyc HBM latency),
// so chunk 1 stages for free. Publishes/target-staging amortize 2x. Raw-load
// regs reused (process(0) consumes before issue(1)) -> ~95 VGPR, (128,4).
// Blocks 1564 x 2 waves: discriminating test -- latency-exposure theory
// predicts ~23us main; raw-wave-count theory predicts ~40.
// Carried: fire-and-forget ds_min (phase-disjoint rotation, 32 distinct
// words/phase), packed-fp32 dot pairs, key-packed top-2 + one-time merge,
// x16 replicated global accumulators, separate finalize (NO fence/counter --
// R12-R15's ~45ns/block fence tax, confirmed removed in R16).

constexpr int KT = 64;
constexpr int P  = 4;
constexpr int NREP = 16;
constexpr float DIST_THRESH = 0.1f;
constexpr float W_DIST    = 0.05f;
constexpr float W_CHAMFER = 0.05f;
constexpr float W_SEP     = 0.0005f;
constexpr float PT_SENT = -1e18f;  // dummy-point sentinel (tail lanes)
constexpr float TG_SENT = -1e18f;  // invalid-target sentinel
constexpr float BIGF  = 3.0e38f;
constexpr float WBIAS = 16.0f;     // |t|^2 + WBIAS in T.w keeps valid keys > 0

typedef float f2 __attribute__((ext_vector_type(2)));

__device__ __forceinline__ unsigned umin_(unsigned a, unsigned b) { return a < b ? a : b; }
__device__ __forceinline__ unsigned umax_(unsigned a, unsigned b) { return a > b ? a : b; }

__device__ __forceinline__ f2 pk_fma(f2 a, f2 b, f2 c) {
#if __has_builtin(__builtin_elementwise_fma)
    return __builtin_elementwise_fma(a, b, c);
#else
    f2 r; r.x = fmaf(a.x, b.x, c.x); r.y = fmaf(a.y, b.y, c.y); return r;
#endif
}

// ws layout: [0,16384) g2p replicas rep*256+b*64+k (encode ~bits(g), init 0);
//            [16384,17408) sums replicas rep*16 + c*4 + b (float, init 0)
__global__ __launch_bounds__(128, 4)
void landmark_main(const float* __restrict__ C, const float* __restrict__ F,
                   const float* __restrict__ tC, const int* __restrict__ tF,
                   const int* __restrict__ classes, int n_classes, int N,
                   unsigned int* __restrict__ g2p_rep, float* __restrict__ sums_rep)
{
    __shared__ float4   tgtFull[KT];   // staged targets (-2t, |t|^2+WBIAS)
    __shared__ unsigned g2pLDS[KT];    // per-target min bits (float >= 0)
    __shared__ uint4    mK1[64], mK2[64];   // wave A -> B merge (lane-indexed,
    __shared__ float4   mLM[64];            //  16B stride: conflict-free)

    const int tid   = threadIdx.x;
    const int lane  = tid & 63;
    const int h     = tid >> 6;        // wave: 0 -> targets [0,32), 1 -> [32,64)
    const int l31   = lane & 31;
    const int hi5   = lane >> 5;       // within-wave 32-lane phase
    const int blk   = blockIdx.x;
    const int b     = blk & 3;
    const int pair  = blk >> 2;        // chunk-pair index
    const int rep   = pair & (NREP - 1);

    // Stage 64 targets: (-2tx,-2ty,-2tz, |t|^2+WBIAS), sentinel if invalid.
    if (tid < KT) {
        int f = tF[b * KT + tid];
        bool valid = false;
        for (int c = 0; c < n_classes; ++c) valid = valid || (f == classes[c]);
        float x = TG_SENT, y = TG_SENT, z = TG_SENT;
        if (valid) {
            x = tC[(b * KT + tid) * 3 + 0];
            y = tC[(b * KT + tid) * 3 + 1];
            z = tC[(b * KT + tid) * 3 + 2];
        }
        tgtFull[tid] = make_float4(-2.f * x, -2.f * y, -2.f * z,
                                   x * x + y * y + z * z + WBIAS);
        g2pLDS[tid] = 0x7F7FFFFFu;     // FLT_MAX bits
    }
    __syncthreads();

    const float*  Cb = C + (size_t)b * N * 3;
    const float4* Fb = (const float4*)(F + (size_t)b * N * 4);
    const int base0 = pair * 512;          // chunk 0: 256 pts
    const int base1 = base0 + 256;         // chunk 1: next 256 pts

    // raw in-flight regs (reused across chunks: processed before next issue)
    float4 rf[P]; float rX[P], rY[P], rZ[P];
    // processed per-chunk state
    f2 pcx[P], pcy[P], pcz[P];
    float ppm[P], ccm[P], f0[P];
    unsigned k1[P], k2[P];
    float lmin[P];
    // running sums across both chunks (wave B)
    float dist_acc = 0.f, p2g_acc = 0.f, sep_acc = 0.f;

    auto issue_loads = [&](int baseN) {
        #pragma unroll
        for (int p = 0; p < P; ++p) {
            int n = baseN + p * 64 + lane;
            int ni = (n < N) ? n : 0;
            rf[p] = Fb[ni];
            rX[p] = Cb[3 * ni + 0];
            rY[p] = Cb[3 * ni + 1];
            rZ[p] = Cb[3 * ni + 2];
        }
    };
    auto process = [&](int baseN) {
        #pragma unroll
        for (int p = 0; p < P; ++p) {
            int n = baseN + p * 64 + lane;
            bool v = (n < N);
            float4 f4 = rf[p];
            float X = rX[p], Y = rY[p], Z = rZ[p];
            // dummy points: coords -> sentinel; f0 -> 0.2 so dist term cancels.
            f0[p] = v ? f4.x : 2.0f * DIST_THRESH;
            if (!v) { X = PT_SENT; Y = PT_SENT; Z = PT_SENT; f4.y = f4.z = f4.w = 0.f; }
            float cxv = X + f4.y, cyv = Y + f4.z, czv = Z + f4.w;
            pcx[p] = (f2){X, cxv};
            pcy[p] = (f2){Y, cyv};
            pcz[p] = (f2){Z, czv};
            ppm[p] = fmaf(Z, Z, fmaf(Y, Y, X * X)) - WBIAS;
            ccm[p] = fmaf(czv, czv, fmaf(cyv, cyv, cxv * cxv)) - WBIAS;
        }
    };

    const unsigned tkb = (unsigned)((l31 ^ (hi5 << 4)) | (h << 5));

    auto do_chunk = [&]() {
        #pragma unroll
        for (int p = 0; p < P; ++p) { k1[p] = 0xFFFFFFFFu; k2[p] = 0xFFFFFFFFu; lmin[p] = BIGF; }

        #pragma unroll 8
        for (int i = 0; i < 32; ++i) {
            const unsigned tk = tkb ^ (unsigned)i;    // this wave's target half;
            const float4 T = tgtFull[tk];             // 32 distinct words/phase
            const f2 Tx = {T.x, T.x}, Ty = {T.y, T.y}, Tz = {T.z, T.z}, Tw = {T.w, T.w};
            float av[P];
            #pragma unroll
            for (int p = 0; p < P; ++p) {
                f2 w2 = pk_fma(pcx[p], Tx, pk_fma(pcy[p], Ty, pk_fma(pcz[p], Tz, Tw)));
                unsigned key = (__float_as_uint(w2.x) & 0xFFFFFFC0u) | tk;
                unsigned hi = umax_(k1[p], key);
                k1[p] = umin_(k1[p], key);
                k2[p] = umin_(k2[p], hi);
                lmin[p] = fminf(lmin[p], w2.y);
                av[p] = w2.y + ccm[p];                // true ld2 for cross-p compare
            }
            float dl = fmaxf(fminf(fminf(av[0], av[1]), fminf(av[2], av[3])), 0.f);
            atomicMin(&g2pLDS[tk], __float_as_uint(dl));  // ds_min_u32, no return
        }

        // wave A publishes its half's per-point state for the merge
        if (h == 0) {
            mK1[lane] = make_uint4(k1[0], k1[1], k1[2], k1[3]);
            mK2[lane] = make_uint4(k2[0], k2[1], k2[2], k2[3]);
            mLM[lane] = make_float4(lmin[0], lmin[1], lmin[2], lmin[3]);
        }
        __syncthreads();   // ds_min complete + merge publish visible

        if (h == 1) {
            // merge halves + per-point epilogue; accumulate across chunks
            uint4 A1 = mK1[lane], A2 = mK2[lane];
            float4 AL = mLM[lane];
            const unsigned a1v[P] = {A1.x, A1.y, A1.z, A1.w};
            const unsigned a2v[P] = {A2.x, A2.y, A2.z, A2.w};
            const float    alv[P] = {AL.x, AL.y, AL.z, AL.w};
            #pragma unroll
            for (int p = 0; p < P; ++p) {
                unsigned m1 = umin_(a1v[p], k1[p]);
                unsigned m2 = umin_(umax_(a1v[p], k1[p]), umin_(a2v[p], k2[p]));
                float lm = fminf(alv[p], lmin[p]);
                float keyf1 = __uint_as_float(m1 & 0xFFFFFFC0u);
                float mind = sqrtf(fmaxf(keyf1 + ppm[p], 0.f));
                bool pm = mind < DIST_THRESH;        // false for dummy (ppm huge)
                float tgtv = fminf(mind, 2.0f * DIST_THRESH);
                float diff = f0[p] - tgtv;
                float ad = fabsf(diff);
                dist_acc += (ad < 1.0f) ? 0.5f * diff * diff : (ad - 0.5f);
                if (pm) {
                    p2g_acc += fmaxf(lm + ccm[p], 0.f);
                    int i1 = (int)(m1 & 63u), i2 = (int)(m2 & 63u);
                    float4 T1 = tgtFull[i1], T2 = tgtFull[i2];
                    float cxv = pcx[p].y, cyv = pcy[p].y, czv = pcz[p].y;
                    float l1sq = fmaf(cxv, T1.x, fmaf(cyv, T1.y, fmaf(czv, T1.z, T1.w))) + ccm[p];
                    float l2sq = fmaf(cxv, T2.x, fmaf(cyv, T2.y, fmaf(czv, T2.z, T2.w))) + ccm[p];
                    sep_acc += sqrtf(fmaxf(l1sq, 0.f) / fmaxf(l2sq, 1e-30f));
                }
            }
        }
        __syncthreads();   // protect mK1/mK2/mLM reuse by next chunk
    };

    // ---- pipelined chunk pair ----
    issue_loads(base0);
    process(base0);        // waitcnt folds here
    issue_loads(base1);    // fire-and-forget: hidden under chunk-0 loop
    do_chunk();
    process(base1);
    do_chunk();

    // ---- final per-block publishes ----
    if (h == 0) {
        // g2pLDS holds bits(g), g>=0; ~bits monotone decreasing -> atomicMax == min.
        atomicMax(&g2p_rep[rep * 256 + b * 64 + lane], ~g2pLDS[lane]);
    } else {
        float v0 = dist_acc, v1 = p2g_acc, v2 = sep_acc;
        #pragma unroll
        for (int o = 32; o > 0; o >>= 1) {
            v0 += __shfl_down(v0, o, 64);
            v1 += __shfl_down(v1, o, 64);
            v2 += __shfl_down(v2, o, 64);
        }
        if (lane == 0) {
            float* sb = sums_rep + rep * 16 + b;
            atomicAdd(sb + 0, v0);
            atomicAdd(sb + 4, v1);
            atomicAdd(sb + 8, v2);
        }
    }
}

__global__ void landmark_finalize(const int* __restrict__ tF, const int* __restrict__ classes,
                                  int n_classes, const unsigned int* __restrict__ g2p_rep,
                                  const float* __restrict__ sums_rep, float* __restrict__ out)
{
    __shared__ float lossb[4];
    const int tid = threadIdx.x;          // 256 threads
    const int b = tid >> 6, k = tid & 63;

    int f = tF[b * KT + k];
    bool valid = false;
    for (int c = 0; c < n_classes; ++c) valid = valid || (f == classes[c]);

    unsigned enc = 0;
    for (int r = 0; r < NREP; ++r) enc = umax_(enc, g2p_rep[r * 256 + b * 64 + k]);
    float g  = valid ? __uint_as_float(~enc) : 0.f;
    float nv = valid ? 1.f : 0.f;

    #pragma unroll
    for (int o = 32; o > 0; o >>= 1) {
        g  += __shfl_down(g, o, 64);
        nv += __shfl_down(nv, o, 64);
    }
    if (k == 0) {
        float sd = 0.f, sp = 0.f, ss = 0.f;
        for (int r = 0; r < NREP; ++r) {
            sd += sums_rep[r * 16 + 0 + b];
            sp += sums_rep[r * 16 + 4 + b];
            ss += sums_rep[r * 16 + 8 + b];
        }
        float sep = (nv >= 2.f) ? ss : 0.f;
        lossb[b] = W_DIST * sd + W_CHAMFER * (sp + g) + W_SEP * sep;
    }
    __syncthreads();
    if (tid == 0)
        out[0] = (lossb[0] + lossb[1] + lossb[2] + lossb[3]) * 0.25f;
}

extern "C" void kernel_launch(void* const* d_in, const int* in_sizes, int n_in,
                              void* d_out, int out_size, void* d_ws, size_t ws_size,
                              hipStream_t stream)
{
    const float* C       = (const float*)d_in[0];   // (B,N,3)
    const float* F       = (const float*)d_in[1];   // (B,N,4)
    const float* tC      = (const float*)d_in[2];   // (B,K,3)
    const int*   tF      = (const int*)d_in[3];     // (B,K)
    const int*   classes = (const int*)d_in[4];     // (6,)
    const int n_classes = in_sizes[4];
    const int B = 4;
    const int N = in_sizes[0] / (3 * B);            // 200000

    unsigned int* g2p_rep  = (unsigned int*)d_ws;
    float*        sums_rep = (float*)((char*)d_ws + NREP * 256 * 4);

    hipMemsetAsync(d_ws, 0, NREP * 256 * 4 + NREP * 16 * 4, stream);

    const int pairs = (N + 511) / 512;              // 391 chunk-pairs per batch
    landmark_main<<<pairs * 4, 128, 0, stream>>>(C, F, tC, tF, classes, n_classes,
                                                 N, g2p_rep, sums_rep);
    landmark_finalize<<<1, 256, 0, stream>>>(tF, classes, n_classes, g2p_rep,
                                             sums_rep, (float*)d_out);
}

// Round 7
// 97.030 us; speedup vs baseline: 1.8331x; 1.0470x over previous
//
#include <hip/hip_runtime.h>

// LandmarkLoss, round 18. B=4, N=200000, K=64.
// Empirical law across fence-free rounds: main ~= wave-iters/CU x instrs x
// 2cyc -- ONE SIMD-equivalent of VALU throughput per CU (4x under HW) at 20%
// VALUBusy. Waves stall ~300cyc/iter: the ds_read_b128 (T) wait sits behind
// fire-and-forget ds_atomic_min ops in the IN-ORDER lgkm FIFO, so every
// T-use pays read latency + queued atomic completion. Occupancy can't fix it
// (R13: 51% occ, no gain).
// R18 = R11's exact 3128-block structure + manual double-banked T-prefetch:
// per 4-iter group, issue next bank's 4 ds_reads FIRST, then compute+atomics.
// Program order [R(g+1)][A(g)] means the in-order drain for bank g+1
// completes reads only (atomics are younger in the FIFO), and reads get a
// full group (~440cyc VALU) of lead time -> wait is free. Banks fully
// unrolled (compile-time indices; no scratch). Prologue: point loads issued
// BEFORE target staging; tC loaded unconditionally (kills the tF->valid->tC
// serial HBM chain).
// Carried: K-split 32/32, P=4, fire-and-forget ds_min, packed-fp32 dot
// pairs, key-packed top-2 + one-time merge, x16 replicated accumulators,
// separate finalize (no fence/counter).

constexpr int KT = 64;
constexpr int P  = 4;
constexpr int NREP = 16;
constexpr float DIST_THRESH = 0.1f;
constexpr float W_DIST    = 0.05f;
constexpr float W_CHAMFER = 0.05f;
constexpr float W_SEP     = 0.0005f;
constexpr float PT_SENT = -1e18f;  // dummy-point sentinel (tail lanes)
constexpr float TG_SENT = -1e18f;  // invalid-target sentinel
constexpr float BIGF  = 3.0e38f;
constexpr float WBIAS = 16.0f;     // |t|^2 + WBIAS in T.w keeps valid keys > 0

typedef float f2 __attribute__((ext_vector_type(2)));

__device__ __forceinline__ unsigned umin_(unsigned a, unsigned b) { return a < b ? a : b; }
__device__ __forceinline__ unsigned umax_(unsigned a, unsigned b) { return a > b ? a : b; }

__device__ __forceinline__ f2 pk_fma(f2 a, f2 b, f2 c) {
#if __has_builtin(__builtin_elementwise_fma)
    return __builtin_elementwise_fma(a, b, c);
#else
    f2 r; r.x = fmaf(a.x, b.x, c.x); r.y = fmaf(a.y, b.y, c.y); return r;
#endif
}

// ws layout: [0,16384) g2p replicas rep*256+b*64+k (encode ~bits(g), init 0);
//            [16384,17408) sums replicas rep*16 + c*4 + b (float, init 0)
__global__ __launch_bounds__(128, 4)
void landmark_main(const float* __restrict__ C, const float* __restrict__ F,
                   const float* __restrict__ tC, const int* __restrict__ tF,
                   const int* __restrict__ classes, int n_classes, int N,
                   unsigned int* __restrict__ g2p_rep, float* __restrict__ sums_rep)
{
    __shared__ float4   tgtFull[KT];   // staged targets (-2t, |t|^2+WBIAS)
    __shared__ unsigned g2pLDS[KT];    // per-target min bits (float >= 0)
    __shared__ uint4    mK1[64], mK2[64];   // wave A -> B merge (lane-indexed,
    __shared__ float4   mLM[64];            //  16B stride: conflict-free)

    const int tid   = threadIdx.x;
    const int lane  = tid & 63;
    const int h     = tid >> 6;        // wave: 0 -> targets [0,32), 1 -> [32,64)
    const int l31   = lane & 31;
    const int hi5   = lane >> 5;       // within-wave 32-lane phase
    const int blk   = blockIdx.x;
    const int b     = blk & 3;
    const int chunk = blk >> 2;
    const int rep   = chunk & (NREP - 1);

    const float*  Cb = C + (size_t)b * N * 3;
    const float4* Fb = (const float4*)(F + (size_t)b * N * 4);
    const int base = chunk * (64 * P);   // block covers 256 points

    // ---- issue point loads FIRST (latency overlaps target staging) ----
    float4 rf[P]; float rX[P], rY[P], rZ[P];
    #pragma unroll
    for (int p = 0; p < P; ++p) {
        int n = base + p * 64 + lane;
        int ni = (n < N) ? n : 0;
        rf[p] = Fb[ni];
        rX[p] = Cb[3 * ni + 0];
        rY[p] = Cb[3 * ni + 1];
        rZ[p] = Cb[3 * ni + 2];
    }

    // Stage 64 targets: (-2tx,-2ty,-2tz, |t|^2+WBIAS), sentinel if invalid.
    // tC loaded unconditionally -- no serial tF->valid->tC HBM chain.
    if (tid < KT) {
        int f = tF[b * KT + tid];
        float x = tC[(b * KT + tid) * 3 + 0];
        float y = tC[(b * KT + tid) * 3 + 1];
        float z = tC[(b * KT + tid) * 3 + 2];
        bool valid = false;
        for (int c = 0; c < n_classes; ++c) valid = valid || (f == classes[c]);
        if (!valid) { x = TG_SENT; y = TG_SENT; z = TG_SENT; }
        tgtFull[tid] = make_float4(-2.f * x, -2.f * y, -2.f * z,
                                   x * x + y * y + z * z + WBIAS);
        g2pLDS[tid] = 0x7F7FFFFFu;     // FLT_MAX bits
    }
    __syncthreads();

    // ---- process the staged points ----
    f2 pcx[P], pcy[P], pcz[P];         // (raw coord, offset coord) packed pairs
    float ppm[P], ccm[P], f0[P];
    #pragma unroll
    for (int p = 0; p < P; ++p) {
        int n = base + p * 64 + lane;
        bool v = (n < N);
        float4 f4 = rf[p];
        float X = rX[p], Y = rY[p], Z = rZ[p];
        // dummy points: coords -> sentinel; f0 -> 0.2 so dist term cancels.
        f0[p] = v ? f4.x : 2.0f * DIST_THRESH;
        if (!v) { X = PT_SENT; Y = PT_SENT; Z = PT_SENT; f4.y = f4.z = f4.w = 0.f; }
        float cxv = X + f4.y, cyv = Y + f4.z, czv = Z + f4.w;
        pcx[p] = (f2){X, cxv};
        pcy[p] = (f2){Y, cyv};
        pcz[p] = (f2){Z, czv};
        ppm[p] = fmaf(Z, Z, fmaf(Y, Y, X * X)) - WBIAS;
        ccm[p] = fmaf(czv, czv, fmaf(cyv, cyv, cxv * cxv)) - WBIAS;
    }

    // keyf = T.w - 2 p.t (= true pd2 - |p|^2 + WBIAS, > 0 for valid pairs)
    unsigned k1[P], k2[P];
    float lmin[P];
    #pragma unroll
    for (int p = 0; p < P; ++p) { k1[p] = 0xFFFFFFFFu; k2[p] = 0xFFFFFFFFu; lmin[p] = BIGF; }

    // Rotation tk = tkb ^ i: per-iteration bijection within the wave's half;
    // same addressing semantics as R11.
    const unsigned tkb = (unsigned)((l31 ^ (hi5 << 4)) | (h << 5));

    // ---- double-banked inner loop: 8 groups x 4 iterations ----
    float4 Tb[2][4];   // fully-unrolled access only (compile-time indices)
    #pragma unroll
    for (int j = 0; j < 4; ++j) Tb[0][j] = tgtFull[tkb ^ (unsigned)j];

    #pragma unroll
    for (int g = 0; g < 8; ++g) {
        const int cur = g & 1, nxt = cur ^ 1;
        // issue next bank's reads BEFORE this group's compute+atomics:
        // lgkm FIFO order [R(g+1)][A(g)] -> draining for R never waits on A.
        if (g < 7) {
            #pragma unroll
            for (int j = 0; j < 4; ++j)
                Tb[nxt][j] = tgtFull[tkb ^ (unsigned)((g + 1) * 4 + j)];
        }
        #pragma unroll
        for (int j = 0; j < 4; ++j) {
            const unsigned tk = tkb ^ (unsigned)(g * 4 + j);
            const float4 T = Tb[cur][j];
            const f2 Tx = {T.x, T.x}, Ty = {T.y, T.y}, Tz = {T.z, T.z}, Tw = {T.w, T.w};
            float av[P];
            #pragma unroll
            for (int p = 0; p < P; ++p) {
                f2 w2 = pk_fma(pcx[p], Tx, pk_fma(pcy[p], Ty, pk_fma(pcz[p], Tz, Tw)));
                unsigned key = (__float_as_uint(w2.x) & 0xFFFFFFC0u) | tk;
                unsigned hi = umax_(k1[p], key);
                k1[p] = umin_(k1[p], key);
                k2[p] = umin_(k2[p], hi);
                lmin[p] = fminf(lmin[p], w2.y);
                av[p] = w2.y + ccm[p];                // true ld2 for cross-p compare
            }
            float dl = fmaxf(fminf(fminf(av[0], av[1]), fminf(av[2], av[3])), 0.f);
            atomicMin(&g2pLDS[tk], __float_as_uint(dl));  // ds_min_u32, no return
        }
    }

    // ---- wave A publishes its half's per-point state for the merge ----
    if (h == 0) {
        mK1[lane] = make_uint4(k1[0], k1[1], k1[2], k1[3]);
        mK2[lane] = make_uint4(k2[0], k2[1], k2[2], k2[3]);
        mLM[lane] = make_float4(lmin[0], lmin[1], lmin[2], lmin[3]);
    }
    __syncthreads();   // ds_min complete + merge publish visible

    if (h == 0) {
        // g2pLDS holds bits(g), g>=0; ~bits monotone decreasing -> atomicMax == min.
        atomicMax(&g2p_rep[rep * 256 + b * 64 + lane], ~g2pLDS[lane]);
    } else {
        // ---- merge halves + epilogue (wave B only) ----
        uint4 A1 = mK1[lane], A2 = mK2[lane];
        float4 AL = mLM[lane];
        const unsigned a1v[P] = {A1.x, A1.y, A1.z, A1.w};
        const unsigned a2v[P] = {A2.x, A2.y, A2.z, A2.w};
        const float    alv[P] = {AL.x, AL.y, AL.z, AL.w};

        float dist_acc = 0.f, p2g_acc = 0.f, sep_acc = 0.f;
        #pragma unroll
        for (int p = 0; p < P; ++p) {
            unsigned m1 = umin_(a1v[p], k1[p]);
            unsigned m2 = umin_(umax_(a1v[p], k1[p]), umin_(a2v[p], k2[p]));
            float lm = fminf(alv[p], lmin[p]);
            float keyf1 = __uint_as_float(m1 & 0xFFFFFFC0u);
            float mind = sqrtf(fmaxf(keyf1 + ppm[p], 0.f));
            bool pm = mind < DIST_THRESH;            // false for dummy (ppm huge)
            float tgtv = fminf(mind, 2.0f * DIST_THRESH);
            float diff = f0[p] - tgtv;
            float ad = fabsf(diff);
            dist_acc += (ad < 1.0f) ? 0.5f * diff * diff : (ad - 0.5f);
            if (pm) {
                p2g_acc += fmaxf(lm + ccm[p], 0.f);
                int i1 = (int)(m1 & 63u), i2 = (int)(m2 & 63u);
                float4 T1 = tgtFull[i1], T2 = tgtFull[i2];
                float cxv = pcx[p].y, cyv = pcy[p].y, czv = pcz[p].y;
                float l1sq = fmaf(cxv, T1.x, fmaf(cyv, T1.y, fmaf(czv, T1.z, T1.w))) + ccm[p];
                float l2sq = fmaf(cxv, T2.x, fmaf(cyv, T2.y, fmaf(czv, T2.z, T2.w))) + ccm[p];
                sep_acc += sqrtf(fmaxf(l1sq, 0.f) / fmaxf(l2sq, 1e-30f));
            }
        }

        float v0 = dist_acc, v1 = p2g_acc, v2 = sep_acc;
        #pragma unroll
        for (int o = 32; o > 0; o >>= 1) {
            v0 += __shfl_down(v0, o, 64);
            v1 += __shfl_down(v1, o, 64);
            v2 += __shfl_down(v2, o, 64);
        }
        if (lane == 0) {
            float* sb = sums_rep + rep * 16 + b;
            atomicAdd(sb + 0, v0);
            atomicAdd(sb + 4, v1);
            atomicAdd(sb + 8, v2);
        }
    }
}

__global__ void landmark_finalize(const int* __restrict__ tF, const int* __restrict__ classes,
                                  int n_classes, const unsigned int* __restrict__ g2p_rep,
                                  const float* __restrict__ sums_rep, float* __restrict__ out)
{
    __shared__ float lossb[4];
    const int tid = threadIdx.x;          // 256 threads
    const int b = tid >> 6, k = tid & 63;

    int f = tF[b * KT + k];
    bool valid = false;
    for (int c = 0; c < n_classes; ++c) valid = valid || (f == classes[c]);

    unsigned enc = 0;
    for (int r = 0; r < NREP; ++r) enc = umax_(enc, g2p_rep[r * 256 + b * 64 + k]);
    float g  = valid ? __uint_as_float(~enc) : 0.f;
    float nv = valid ? 1.f : 0.f;

    #pragma unroll
    for (int o = 32; o > 0; o >>= 1) {
        g  += __shfl_down(g, o, 64);
        nv += __shfl_down(nv, o, 64);
    }
    if (k == 0) {
        float sd = 0.f, sp = 0.f, ss = 0.f;
        for (int r = 0; r < NREP; ++r) {
            sd += sums_rep[r * 16 + 0 + b];
            sp += sums_rep[r * 16 + 4 + b];
            ss += sums_rep[r * 16 + 8 + b];
        }
        float sep = (nv >= 2.f) ? ss : 0.f;
        lossb[b] = W_DIST * sd + W_CHAMFER * (sp + g) + W_SEP * sep;
    }
    __syncthreads();
    if (tid == 0)
        out[0] = (lossb[0] + lossb[1] + lossb[2] + lossb[3]) * 0.25f;
}

extern "C" void kernel_launch(void* const* d_in, const int* in_sizes, int n_in,
                              void* d_out, int out_size, void* d_ws, size_t ws_size,
                              hipStream_t stream)
{
    const float* C       = (const float*)d_in[0];   // (B,N,3)
    const float* F       = (const float*)d_in[1];   // (B,N,4)
    const float* tC      = (const float*)d_in[2];   // (B,K,3)
    const int*   tF      = (const int*)d_in[3];     // (B,K)
    const int*   classes = (const int*)d_in[4];     // (6,)
    const int n_classes = in_sizes[4];
    const int B = 4;
    const int N = in_sizes[0] / (3 * B);            // 200000

    unsigned int* g2p_rep  = (unsigned int*)d_ws;
    float*        sums_rep = (float*)((char*)d_ws + NREP * 256 * 4);

    hipMemsetAsync(d_ws, 0, NREP * 256 * 4 + NREP * 16 * 4, stream);

    const int cpb = (N + 64 * P - 1) / (64 * P);    // 782 chunks per batch
    landmark_main<<<cpb * 4, 128, 0, stream>>>(C, F, tC, tF, classes, n_classes,
                                               N, g2p_rep, sums_rep);
    landmark_finalize<<<1, 256, 0, stream>>>(tF, classes, n_classes, g2p_rep,
                                             sums_rep, (float*)d_out);
}